// Round 15
// baseline (136.251 us; speedup 1.0000x reference)
//
#include <hip/hip_runtime.h>

#define NN   100000
#define NE   1600000
#define NH   4
#define FIN  128
#define FOUT 32
#define HF   128
#define SLOPE 0.2f

#define PBKT  64                    // dst nodes per partition bucket
#define PNB   ((NN+PBKT-1)/PBKT)    // 1563 buckets
#define CAP   2048                  // slots per bucket (mean 1024, sd 32)
#define NMF   1563                  // mfma tiles (64 nodes each)
#define NMFB  782                   // mfma blocks (2 tiles each)
#define NPART 391                   // partition blocks (4096 edges each)
#define DSLOT 48                    // lcsr slots per dst (mean 16, +8 sigma)

typedef __attribute__((ext_vector_type(8))) short short8v;   // 8 bf16 (4 VGPRs)
typedef __attribute__((ext_vector_type(4))) float f32x4;

__device__ __forceinline__ unsigned int bpack(float lo, float hi){
    unsigned int ul = __float_as_uint(lo), uh = __float_as_uint(hi);
    ul = (ul + 0x7fffu + ((ul>>16)&1u)) >> 16;
    uh = (uh + 0x7fffu + ((uh>>16)&1u)) >> 16;
    return ul | (uh<<16);
}
__device__ __forceinline__ short bf16of(float f){
    unsigned int u = __float_as_uint(f);
    return (short)((u + 0x7fffu + ((u>>16)&1u)) >> 16);
}
__device__ __forceinline__ float blo(unsigned int u){ return __uint_as_float(u<<16); }
__device__ __forceinline__ float bhi(unsigned int u){ return __uint_as_float(u&0xffff0000u); }

// ---- kernel 0: one-block prep (unchanged) ----
__global__ __launch_bounds__(1024) void prep_k(
    const float* __restrict__ w, const float* __restrict__ a,
    short* __restrict__ wfrag, short* __restrict__ wafrag,
    int* __restrict__ cnt)
{
    __shared__ float wal[1024];            // wa[8][128]
    int t = threadIdx.x;
    {
        int s = t>>7, f = t&127, h = s&3;
        const float* ap = a + h*64 + (s>>2)*32;
        const float* wp = w + (size_t)h*4096 + f*32;
        float acc = 0.f;
        #pragma unroll
        for (int o=0;o<32;o++) acc = fmaf(wp[o], ap[o], acc);
        wal[s*128 + f] = acc;
    }
    __syncthreads();
    for (int idx=t; idx<2048; idx+=1024){
        int lane = idx&63, ks=(idx>>6)&3, cf=(idx>>8)&1, wvv=idx>>9;
        int col = wvv*32 + cf*16 + (lane&15);
        int fb  = ks*32 + (lane>>4)*8;
        const float* wp = w + (size_t)(col>>5)*4096 + (col&31);
        short8v bv;
        #pragma unroll
        for (int j=0;j<8;j++) bv[j] = bf16of(wp[(size_t)(fb+j)*32]);
        ((short8v*)wfrag)[idx] = bv;
    }
    if (t < 256){
        int lane = t&63, ks = t>>6;
        int l15 = lane&15, fb = ks*32 + (lane>>4)*8;
        short8v bv;
        #pragma unroll
        for (int j=0;j<8;j++) bv[j] = (l15<8) ? bf16of(wal[l15*128 + fb + j]) : (short)0;
        ((short8v*)wafrag)[t] = bv;
    }
    for (int i=t;i<PNB;i+=1024) cnt[i]=0;
}

// ---- fused kernel macros ----
#define STAGE_TILE(n0, ldsb) do{                                          \
    _Pragma("unroll")                                                     \
    for (int p=0; p<8; ++p){                                              \
        int r  = p*8 + (t>>5); int cq = t & 31;                           \
        int nr = (n0) + r; if (nr > NN-1) nr = NN-1;                      \
        float4 v = *(const float4*)(x + (size_t)nr*FIN + cq*4);           \
        int cb = (cq*8) ^ ((r&7)<<4);                                     \
        *(uint2*)((ldsb) + r*256 + cb) =                                  \
            make_uint2(bpack(v.x,v.y), bpack(v.z,v.w));                   \
    } }while(0)

#define ZERO_C() do{                                                      \
    _Pragma("unroll") for (int rt=0;rt<4;rt++)                            \
    _Pragma("unroll") for (int cf=0;cf<3;cf++){                           \
        f32x4 z = {0.f,0.f,0.f,0.f}; C[rt][cf] = z; } }while(0)

#define DO_MFMA(ldsb) do{                                                 \
    _Pragma("unroll")                                                     \
    for (int rt=0; rt<4; ++rt){                                           \
        int row = rt*16 + l15;                                            \
        const char* arow = (ldsb) + row*256;                              \
        short8v Af[4];                                                    \
        _Pragma("unroll")                                                 \
        for (int ks=0; ks<4; ++ks)                                        \
            Af[ks] = *(const short8v*)(arow + (((ks<<6)|(lk<<1)) ^ axor));\
        _Pragma("unroll")                                                 \
        for (int ks=0; ks<4; ++ks){                                       \
            C[rt][0] = __builtin_amdgcn_mfma_f32_16x16x32_bf16(Af[ks], Bf[0][ks], C[rt][0], 0,0,0); \
            C[rt][1] = __builtin_amdgcn_mfma_f32_16x16x32_bf16(Af[ks], Bf[1][ks], C[rt][1], 0,0,0); \
            if (wv==0)                                                    \
                C[rt][2] = __builtin_amdgcn_mfma_f32_16x16x32_bf16(Af[ks], Bf[2][ks], C[rt][2], 0,0,0); \
        } } }while(0)

#define EPILOGUE(n0) do{                                                  \
    _Pragma("unroll")                                                     \
    for (int rt=0; rt<4; ++rt){                                           \
        _Pragma("unroll")                                                 \
        for (int cf=0; cf<2; ++cf){                                       \
            f32x4 c = C[rt][cf];                                          \
            _Pragma("unroll")                                             \
            for (int i=0;i<4;i++){                                        \
                float v1 = __shfl_xor(c[i], 1);                           \
                float v2 = __shfl_xor(c[i], 2);                           \
                float v3 = __shfl_xor(c[i], 3);                           \
                int node = (n0) + rt*16 + ((lane>>4)<<2) + i;             \
                if ((l15&3)==0 && node < NN){                             \
                    uint2 pk = make_uint2(bpack(c[i], v1), bpack(v2, v3));\
                    *(uint2*)(hb + (size_t)node*64 + wv*16 + cf*8 + g4*2) = pk; \
                } } } }                                                   \
    if (wv==0 && l15 < 8){                                                \
        _Pragma("unroll")                                                 \
        for (int rt=0; rt<4; ++rt){                                       \
            f32x4 c = C[rt][2];                                           \
            _Pragma("unroll")                                             \
            for (int i=0;i<4;i++){                                        \
                int node = (n0) + rt*16 + ((lane>>4)<<2) + i;             \
                if (node < NN){                                           \
                    if (l15 < 4) asrc[(size_t)node*4 + l15]     = c[i];   \
                    else         adst[(size_t)node*4 + (l15-4)] = c[i];   \
                } } } } }while(0)

// ---- kernel 1: FUSED role-split; mfma blocks process 2 tiles pipelined.
// bid%3==2: partition (4096 edges). else: mfma, tiles 2*mIdx, 2*mIdx+1.
__global__ __launch_bounds__(256) void fused_k(
    const float* __restrict__ x, const short* __restrict__ wfrag,
    const short* __restrict__ wafrag, unsigned int* __restrict__ hb,
    float* __restrict__ asrc, float* __restrict__ adst,
    const int* __restrict__ esrc, const int* __restrict__ edst,
    int* __restrict__ cnt, unsigned int* __restrict__ parr)
{
    __shared__ __align__(16) char smem[32768];   // 2 A-tile bufs / part hist+bcur
    const int bid = blockIdx.x;
    const int t   = threadIdx.x;

    if (bid % 3 == 2){
        // ---------- partition role: 4096 edges ----------
        int* hist = (int*)smem;
        int* bcur = hist + PNB;
        for (int i=t;i<PNB;i+=256) hist[i]=0;
        __syncthreads();
        int base = (bid/3)*4096;
        #pragma unroll
        for (int k=0;k<16;k++){
            int e = base + k*256 + t;
            if (e < NE) atomicAdd(&hist[edst[e]>>6], 1);
        }
        __syncthreads();
        for (int i=t;i<PNB;i+=256)
            bcur[i] = hist[i] ? atomicAdd(&cnt[i], hist[i]) : 0;
        __syncthreads();
        #pragma unroll
        for (int k=0;k<16;k++){
            int e = base + k*256 + t;
            if (e < NE){
                int d = edst[e], s = esrc[e];
                int pos = atomicAdd(&bcur[d>>6], 1);
                parr[(size_t)(d>>6)*CAP + pos] = ((unsigned int)s<<6) | (unsigned int)(d & 63);
            }
        }
        return;
    }

    // ---------- mfma role: 2 tiles ----------
    const int mIdx = (bid/3)*2 + (bid%3);
    const int mi0 = mIdx*2, mi1 = mi0 + 1;
    const bool has1 = (mi1 < NMF);
    char* buf0 = smem;
    char* buf1 = smem + 16384;

    const int wv   = t>>6;
    const int lane = t&63;
    const int l15  = lane&15;
    const int lk   = (lane>>4)<<3;
    const int axor = (lane&7)<<4;
    const int g4   = l15>>2;

    STAGE_TILE(mi0*64, buf0);
    __syncthreads();

    // B fragments (shared by both tiles)
    short8v Bf[3][4];
    const short8v* wf  = (const short8v*)wfrag;
    const short8v* waf = (const short8v*)wafrag;
    #pragma unroll
    for (int cf=0; cf<2; ++cf)
        #pragma unroll
        for (int ks=0; ks<4; ++ks)
            Bf[cf][ks] = wf[((wv*2+cf)*4+ks)*64 + lane];
    #pragma unroll
    for (int ks=0; ks<4; ++ks) Bf[2][ks] = waf[ks*64 + lane];

    // issue tile-1 global loads EARLY (held in regs; latency hides under MFMA0)
    float4 xr0,xr1,xr2,xr3,xr4,xr5,xr6,xr7;
    if (has1){
        const int cq = t&31;
        #define LOADX(p, dst) { int r=(p)*8+(t>>5); int nr=mi1*64+r; if(nr>NN-1)nr=NN-1; \
                                dst = *(const float4*)(x + (size_t)nr*FIN + cq*4); }
        LOADX(0,xr0) LOADX(1,xr1) LOADX(2,xr2) LOADX(3,xr3)
        LOADX(4,xr4) LOADX(5,xr5) LOADX(6,xr6) LOADX(7,xr7)
        #undef LOADX
    }

    f32x4 C[4][3];
    ZERO_C();
    DO_MFMA(buf0);

    // write tile-1 to buf1 (after MFMA0 issued; vmcnt waits happen here)
    if (has1){
        const int cq = t&31;
        #define WRX(p, src) { int r=(p)*8+(t>>5); int cb=(cq*8)^((r&7)<<4); \
            *(uint2*)(buf1 + r*256 + cb) = make_uint2(bpack(src.x,src.y), bpack(src.z,src.w)); }
        WRX(0,xr0) WRX(1,xr1) WRX(2,xr2) WRX(3,xr3)
        WRX(4,xr4) WRX(5,xr5) WRX(6,xr6) WRX(7,xr7)
        #undef WRX
    }

    EPILOGUE(mi0*64);
    __syncthreads();

    if (has1){
        ZERO_C();
        DO_MFMA(buf1);
        EPILOGUE(mi1*64);
    }
}

// ---- gather macros ----
#define ACC2(x0,x1,u0,u1,adh,ss,ac) do{                                   \
    float _v0=(x0)+(adh); _v0=fmaxf(_v0,SLOPE*_v0); float _p0=__expf(_v0);\
    float _v1=(x1)+(adh); _v1=fmaxf(_v1,SLOPE*_v1); float _p1=__expf(_v1);\
    ss += _p0+_p1;                                                        \
    ac[0]=fmaf(_p0,blo(u0.x),fmaf(_p1,blo(u1.x),ac[0]));                  \
    ac[1]=fmaf(_p0,bhi(u0.x),fmaf(_p1,bhi(u1.x),ac[1]));                  \
    ac[2]=fmaf(_p0,blo(u0.y),fmaf(_p1,blo(u1.y),ac[2]));                  \
    ac[3]=fmaf(_p0,bhi(u0.y),fmaf(_p1,bhi(u1.y),ac[3]));                  \
    ac[4]=fmaf(_p0,blo(u0.z),fmaf(_p1,blo(u1.z),ac[4]));                  \
    ac[5]=fmaf(_p0,bhi(u0.z),fmaf(_p1,bhi(u1.z),ac[5]));                  \
    ac[6]=fmaf(_p0,blo(u0.w),fmaf(_p1,blo(u1.w),ac[6]));                  \
    ac[7]=fmaf(_p0,bhi(u0.w),fmaf(_p1,bhi(u1.w),ac[7])); }while(0)

#define ACC1(x0,u0,adh,ss,ac) do{                                         \
    float _v0=(x0)+(adh); _v0=fmaxf(_v0,SLOPE*_v0); float _p0=__expf(_v0);\
    ss += _p0;                                                            \
    ac[0]=fmaf(_p0,blo(u0.x),ac[0]); ac[1]=fmaf(_p0,bhi(u0.x),ac[1]);     \
    ac[2]=fmaf(_p0,blo(u0.y),ac[2]); ac[3]=fmaf(_p0,bhi(u0.y),ac[3]);     \
    ac[4]=fmaf(_p0,blo(u0.z),ac[4]); ac[5]=fmaf(_p0,bhi(u0.z),ac[5]);     \
    ac[6]=fmaf(_p0,blo(u0.w),ac[6]); ac[7]=fmaf(_p0,bhi(u0.w),ac[7]); }while(0)

#define DRAIN8(basek,kk,mm,adh,ss,ac)                                     \
    for (; kk+8<=mm; kk+=8){                                              \
        int _s0=lcsr[(basek)+kk+q], _s1=lcsr[(basek)+kk+4+q];             \
        float _a0=asrc[(size_t)_s0*NH+head], _a1=asrc[(size_t)_s1*NH+head];\
        uint4 _u0=hb4[(size_t)_s0*16+l15], _u1=hb4[(size_t)_s1*16+l15];   \
        ACC2(_a0,_a1,_u0,_u1,adh,ss,ac);                                  \
    }                                                                     \
    for (; kk<mm; kk+=4){                                                 \
        int _r=mm-kk;                                                     \
        if (q<_r){                                                        \
            int _s0=lcsr[(basek)+kk+q];                                   \
            float _a0=asrc[(size_t)_s0*NH+head];                          \
            uint4 _u0=hb4[(size_t)_s0*16+l15];                            \
            ACC1(_a0,_u0,adh,ss,ac);                                      \
        } }

#define REDUCE_STORE(d,ss,ac) do{                                         \
    ss += __shfl_xor(ss,16); ss += __shfl_xor(ss,32);                     \
    ac[0]+=__shfl_xor(ac[0],16); ac[0]+=__shfl_xor(ac[0],32);             \
    ac[1]+=__shfl_xor(ac[1],16); ac[1]+=__shfl_xor(ac[1],32);             \
    ac[2]+=__shfl_xor(ac[2],16); ac[2]+=__shfl_xor(ac[2],32);             \
    ac[3]+=__shfl_xor(ac[3],16); ac[3]+=__shfl_xor(ac[3],32);             \
    ac[4]+=__shfl_xor(ac[4],16); ac[4]+=__shfl_xor(ac[4],32);             \
    ac[5]+=__shfl_xor(ac[5],16); ac[5]+=__shfl_xor(ac[5],32);             \
    ac[6]+=__shfl_xor(ac[6],16); ac[6]+=__shfl_xor(ac[6],32);             \
    ac[7]+=__shfl_xor(ac[7],16); ac[7]+=__shfl_xor(ac[7],32);             \
    if (q==0){                                                            \
        float inv = 1.f/(ss + 1e-16f);                                    \
        float4 o0 = make_float4(ac[0]*inv+bi0.x, ac[1]*inv+bi0.y,         \
                                ac[2]*inv+bi0.z, ac[3]*inv+bi0.w);        \
        float4 o1 = make_float4(ac[4]*inv+bi1.x, ac[5]*inv+bi1.y,         \
                                ac[6]*inv+bi1.z, ac[7]*inv+bi1.w);        \
        float* op = out + (size_t)(d)*HF + 8*l15;                         \
        *(float4*)op = o0; *(float4*)(op+4) = o1;                         \
    } }while(0)

// ---- kernel 2: one block/bucket; dual-dst-stream quarter-wave gather ----
__global__ __launch_bounds__(256) void gather_k(
    const int* __restrict__ cnt,
    const unsigned int* __restrict__ parr,
    const float* __restrict__ asrc, const float* __restrict__ adst,
    const unsigned int* __restrict__ hb, const float* __restrict__ bias,
    float* __restrict__ out)
{
    __shared__ int lcur[PBKT];
    __shared__ int lcsr[PBKT*DSLOT];       // 12 KB
    const int bkt = blockIdx.x;
    const int t = threadIdx.x;
    int cb = cnt[bkt]; if (cb > CAP) cb = CAP;
    const unsigned int* pb = parr + (size_t)bkt*CAP;

    if (t < PBKT) lcur[t] = 0;
    __syncthreads();
    for (int i=t; i<cb; i+=256){
        unsigned int en = pb[i];
        int dl = (int)(en & 63u);
        int pos = atomicAdd(&lcur[dl], 1);
        if (pos < DSLOT) lcsr[dl*DSLOT + pos] = (int)(en >> 6);
    }
    __syncthreads();

    const int wv   = t>>6;
    const int lane = t&63;
    const int q    = lane>>4;
    const int l15  = lane&15;
    const int head = l15>>2;
    const uint4* hb4 = (const uint4*)hb;
    const float4 bi0 = *(const float4*)(bias + 8*l15);
    const float4 bi1 = *(const float4*)(bias + 8*l15 + 4);

    for (int dl = wv; dl < 32; dl += 4){
        int dA = bkt*PBKT + dl, dB = dA + 32;
        bool vB = (dB < NN);
        int mA = lcur[dl];      if (mA > DSLOT) mA = DSLOT;
        int mB = vB ? lcur[dl+32] : 0; if (mB > DSLOT) mB = DSLOT;
        const int baseA = dl*DSLOT, baseB = (dl+32)*DSLOT;
        float adA = adst[(size_t)dA*NH + head];
        float adB = vB ? adst[(size_t)dB*NH + head] : 0.f;
        float sA = 0.f, sB = 0.f;
        float aA[8] = {0.f,0.f,0.f,0.f,0.f,0.f,0.f,0.f};
        float aB[8] = {0.f,0.f,0.f,0.f,0.f,0.f,0.f,0.f};

        int kA = 0, kB = 0;
        // paired main loop: both streams' loads issued before either's math
        for (; kA+8 <= mA && kB+8 <= mB; kA += 8, kB += 8){
            int sa0 = lcsr[baseA+kA+q],  sa1 = lcsr[baseA+kA+4+q];
            int sb0 = lcsr[baseB+kB+q],  sb1 = lcsr[baseB+kB+4+q];
            float xa0 = asrc[(size_t)sa0*NH+head], xa1 = asrc[(size_t)sa1*NH+head];
            float xb0 = asrc[(size_t)sb0*NH+head], xb1 = asrc[(size_t)sb1*NH+head];
            uint4 ua0 = hb4[(size_t)sa0*16+l15], ua1 = hb4[(size_t)sa1*16+l15];
            uint4 ub0 = hb4[(size_t)sb0*16+l15], ub1 = hb4[(size_t)sb1*16+l15];
            ACC2(xa0,xa1,ua0,ua1,adA,sA,aA);
            ACC2(xb0,xb1,ub0,ub1,adB,sB,aB);
        }
        DRAIN8(baseA,kA,mA,adA,sA,aA);
        DRAIN8(baseB,kB,mB,adB,sB,aB);

        REDUCE_STORE(dA,sA,aA);
        if (vB) REDUCE_STORE(dB,sB,aB);
    }
}

extern "C" void kernel_launch(void* const* d_in, const int* in_sizes, int n_in,
                              void* d_out, int out_size, void* d_ws, size_t ws_size,
                              hipStream_t stream)
{
    const float* x    = (const float*)d_in[0];
    const float* w    = (const float*)d_in[1];
    const float* a    = (const float*)d_in[2];
    const float* bias = (const float*)d_in[3];
    const int* esrc   = (const int*)d_in[4];
    const int* edst   = (const int*)d_in[5];
    float* out = (float*)d_out;

    // ws: wfrag s16[16384] | wafrag s16[2048] | hb u32[NN*64] | asrc f32[NN*4]
    //   | adst f32[NN*4] | parr u32[PNB*CAP] | cnt i32[PNB]
    short* wfrag  = (short*)d_ws;
    short* wafrag = wfrag + 16384;
    unsigned int* hb = (unsigned int*)(wafrag + 2048);
    float* as   = (float*)(hb + (size_t)NN*64);
    float* ad   = as + (size_t)NN*NH;
    unsigned int* parr = (unsigned int*)(ad + (size_t)NN*NH);
    int* cnt    = (int*)(parr + (size_t)PNB*CAP);

    hipLaunchKernelGGL(prep_k, dim3(1), dim3(1024), 0, stream,
                       w, a, wfrag, wafrag, cnt);
    hipLaunchKernelGGL(fused_k, dim3(NMFB + NPART), dim3(256), 0, stream,
                       x, wfrag, wafrag, hb, as, ad, esrc, edst, cnt, parr);
    hipLaunchKernelGGL(gather_k, dim3(PNB), dim3(256), 0, stream,
                       cnt, parr, as, ad, hb, bias, out);
}

// Round 16
// 127.645 us; speedup vs baseline: 1.0674x; 1.0674x over previous
//
#include <hip/hip_runtime.h>

#define NN   100000
#define NE   1600000
#define NH   4
#define FIN  128
#define FOUT 32
#define HF   128
#define SLOPE 0.2f

#define PBKT  64                    // dst nodes per partition bucket
#define PNB   ((NN+PBKT-1)/PBKT)    // 1563 buckets
#define CAP   2048                  // slots per bucket (mean 1024, sd 32)
#define NMF   1563                  // mfma blocks (64 nodes each)
#define NPART 391                   // partition blocks (4096 edges each)
#define DSLOT 48                    // lcsr slots per dst (mean 16, +8 sigma)

typedef __attribute__((ext_vector_type(8))) short short8v;   // 8 bf16 (4 VGPRs)
typedef __attribute__((ext_vector_type(4))) float f32x4;

__device__ __forceinline__ unsigned int bpack(float lo, float hi){
    unsigned int ul = __float_as_uint(lo), uh = __float_as_uint(hi);
    ul = (ul + 0x7fffu + ((ul>>16)&1u)) >> 16;
    uh = (uh + 0x7fffu + ((uh>>16)&1u)) >> 16;
    return ul | (uh<<16);
}
__device__ __forceinline__ short bf16of(float f){
    unsigned int u = __float_as_uint(f);
    return (short)((u + 0x7fffu + ((u>>16)&1u)) >> 16);
}
__device__ __forceinline__ float blo(unsigned int u){ return __uint_as_float(u<<16); }
__device__ __forceinline__ float bhi(unsigned int u){ return __uint_as_float(u&0xffff0000u); }

// ---- kernel 0: one-block prep. bf16 MFMA B-fragments of W and W@a; zero cnt.
__global__ __launch_bounds__(1024) void prep_k(
    const float* __restrict__ w, const float* __restrict__ a,
    short* __restrict__ wfrag, short* __restrict__ wafrag,
    int* __restrict__ cnt)
{
    __shared__ float wal[1024];            // wa[8][128]
    int t = threadIdx.x;
    {
        int s = t>>7, f = t&127, h = s&3;
        const float* ap = a + h*64 + (s>>2)*32;
        const float* wp = w + (size_t)h*4096 + f*32;
        float acc = 0.f;
        #pragma unroll
        for (int o=0;o<32;o++) acc = fmaf(wp[o], ap[o], acc);
        wal[s*128 + f] = acc;
    }
    __syncthreads();
    for (int idx=t; idx<2048; idx+=1024){
        int lane = idx&63, ks=(idx>>6)&3, cf=(idx>>8)&1, wvv=idx>>9;
        int col = wvv*32 + cf*16 + (lane&15);
        int fb  = ks*32 + (lane>>4)*8;
        const float* wp = w + (size_t)(col>>5)*4096 + (col&31);
        short8v bv;
        #pragma unroll
        for (int j=0;j<8;j++) bv[j] = bf16of(wp[(size_t)(fb+j)*32]);
        ((short8v*)wfrag)[idx] = bv;
    }
    if (t < 256){
        int lane = t&63, ks = t>>6;
        int l15 = lane&15, fb = ks*32 + (lane>>4)*8;
        short8v bv;
        #pragma unroll
        for (int j=0;j<8;j++) bv[j] = (l15<8) ? bf16of(wal[l15*128 + fb + j]) : (short)0;
        ((short8v*)wafrag)[t] = bv;
    }
    for (int i=t;i<PNB;i+=1024) cnt[i]=0;
}

// ---- kernel 1: FUSED role-split kernel (R13 geometry, cheap epilogue).
// blocks with bid%5==4: edge partition (4096 edges). others: 64-node MFMA h=x@W.
__global__ __launch_bounds__(256) void fused_k(
    const float* __restrict__ x, const short* __restrict__ wfrag,
    const short* __restrict__ wafrag, unsigned int* __restrict__ hb,
    float* __restrict__ asrc, float* __restrict__ adst,
    const int* __restrict__ esrc, const int* __restrict__ edst,
    int* __restrict__ cnt, unsigned int* __restrict__ parr)
{
    __shared__ __align__(16) char smem[16384];   // mfma A-tile / part hist+bcur
    const int bid = blockIdx.x;
    const int t   = threadIdx.x;
    const int r5  = bid % 5;

    if (r5 == 4){
        // ---------- partition role: 4096 edges ----------
        int* hist = (int*)smem;
        int* bcur = hist + PNB;
        for (int i=t;i<PNB;i+=256) hist[i]=0;
        __syncthreads();
        int base = (bid/5)*4096;
        #pragma unroll
        for (int k=0;k<16;k++){
            int e = base + k*256 + t;
            if (e < NE) atomicAdd(&hist[edst[e]>>6], 1);
        }
        __syncthreads();
        for (int i=t;i<PNB;i+=256)
            bcur[i] = hist[i] ? atomicAdd(&cnt[i], hist[i]) : 0;
        __syncthreads();
        #pragma unroll
        for (int k=0;k<16;k++){
            int e = base + k*256 + t;
            if (e < NE){
                int d = edst[e], s = esrc[e];
                int pos = atomicAdd(&bcur[d>>6], 1);
                parr[(size_t)(d>>6)*CAP + pos] = ((unsigned int)s<<6) | (unsigned int)(d & 63);
            }
        }
        return;
    }

    // ---------- mfma role ----------
    const int mi = (bid/5)*4 + r5;
    if (mi >= NMF) return;
    char* lds = smem;
    const int n0 = mi*64;

    #pragma unroll
    for (int p=0; p<8; ++p){
        int r  = p*8 + (t>>5);
        int cq = t & 31;
        int nr = n0 + r; if (nr > NN-1) nr = NN-1;
        float4 v = *(const float4*)(x + (size_t)nr*FIN + cq*4);
        unsigned int lo = bpack(v.x, v.y), hi = bpack(v.z, v.w);
        int cb = (cq*8) ^ ((r&7)<<4);
        *(uint2*)(lds + r*256 + cb) = make_uint2(lo, hi);
    }
    __syncthreads();

    const int wv   = t>>6;
    const int lane = t&63;
    const int l15  = lane&15;
    const int lk   = (lane>>4)<<3;

    short8v Bf[3][4];
    const short8v* wf  = (const short8v*)wfrag;
    const short8v* waf = (const short8v*)wafrag;
    #pragma unroll
    for (int cf=0; cf<2; ++cf)
        #pragma unroll
        for (int ks=0; ks<4; ++ks)
            Bf[cf][ks] = wf[((wv*2+cf)*4+ks)*64 + lane];
    if (wv==0){
        #pragma unroll
        for (int ks=0; ks<4; ++ks) Bf[2][ks] = waf[ks*64 + lane];
    }

    f32x4 C[4][3];
    #pragma unroll
    for (int rt=0;rt<4;rt++)
        #pragma unroll
        for (int cf=0;cf<3;cf++){ f32x4 z = {0.f,0.f,0.f,0.f}; C[rt][cf] = z; }

    const int axor = (lane&7)<<4;
    #pragma unroll
    for (int rt=0; rt<4; ++rt){
        int row = rt*16 + l15;
        const char* arow = lds + row*256;
        short8v Af[4];
        #pragma unroll
        for (int ks=0; ks<4; ++ks)
            Af[ks] = *(const short8v*)(arow + (((ks<<6) | (lk<<1)) ^ axor));
        #pragma unroll
        for (int ks=0; ks<4; ++ks){
            C[rt][0] = __builtin_amdgcn_mfma_f32_16x16x32_bf16(Af[ks], Bf[0][ks], C[rt][0], 0,0,0);
            C[rt][1] = __builtin_amdgcn_mfma_f32_16x16x32_bf16(Af[ks], Bf[1][ks], C[rt][1], 0,0,0);
            if (wv==0)
                C[rt][2] = __builtin_amdgcn_mfma_f32_16x16x32_bf16(Af[ks], Bf[2][ks], C[rt][2], 0,0,0);
        }
    }

    // cheap epilogue: pair adjacent cols with ONE shfl, u32 stores from even lanes
    #pragma unroll
    for (int rt=0; rt<4; ++rt){
        #pragma unroll
        for (int cf=0; cf<2; ++cf){
            f32x4 c = C[rt][cf];
            #pragma unroll
            for (int i=0;i<4;i++){
                float v1 = __shfl_xor(c[i], 1);        // partner column
                int node = n0 + rt*16 + ((lane>>4)<<2) + i;
                if (!(l15&1) && node < NN)
                    hb[(size_t)node*64 + wv*16 + cf*8 + (l15>>1)] = bpack(c[i], v1);
            }
        }
    }
    if (wv==0 && l15 < 8){
        #pragma unroll
        for (int rt=0; rt<4; ++rt){
            f32x4 c = C[rt][2];
            #pragma unroll
            for (int i=0;i<4;i++){
                int node = n0 + rt*16 + ((lane>>4)<<2) + i;
                if (node < NN){
                    if (l15 < 4) asrc[(size_t)node*4 + l15]     = c[i];
                    else         adst[(size_t)node*4 + (l15-4)] = c[i];
                }
            }
        }
    }
}

// ---- kernel 2: one block per bucket; single-pass fixed-slot CSR build,
// then quarter-wave-per-edge math loop (uint4 hb reads, 8 ch/lane). [R12 best]
__global__ __launch_bounds__(256) void gather_k(
    const int* __restrict__ cnt,
    const unsigned int* __restrict__ parr,
    const float* __restrict__ asrc, const float* __restrict__ adst,
    const unsigned int* __restrict__ hb, const float* __restrict__ bias,
    float* __restrict__ out)
{
    __shared__ int lcur[PBKT];
    __shared__ int lcsr[PBKT*DSLOT];       // 12 KB
    const int bkt = blockIdx.x;
    const int t = threadIdx.x;
    int cb = cnt[bkt]; if (cb > CAP) cb = CAP;
    const unsigned int* pb = parr + (size_t)bkt*CAP;

    if (t < PBKT) lcur[t] = 0;
    __syncthreads();
    for (int i=t; i<cb; i+=256){
        unsigned int en = pb[i];
        int dl = (int)(en & 63u);
        int pos = atomicAdd(&lcur[dl], 1);
        if (pos < DSLOT) lcsr[dl*DSLOT + pos] = (int)(en >> 6);
    }
    __syncthreads();

    const int wv   = t>>6;
    const int lane = t&63;
    const int q    = lane>>4;          // quarter owns edge k+q
    const int l15  = lane&15;          // 8 channels: 8*l15 .. 8*l15+7
    const int head = l15>>2;
    const uint4* hb4 = (const uint4*)hb;   // row = 16 uint4
    const float4 bi0 = *(const float4*)(bias + 8*l15);
    const float4 bi1 = *(const float4*)(bias + 8*l15 + 4);

    for (int dl = wv; dl < PBKT; dl += 4){
        int d = bkt*PBKT + dl;
        if (d >= NN) break;
        int m = lcur[dl]; if (m > DSLOT) m = DSLOT;
        const int base = dl*DSLOT;

        float ad_h = adst[(size_t)d*NH + head];
        float ssum = 0.f;
        float ac0=0.f, ac1=0.f, ac2=0.f, ac3=0.f, ac4=0.f, ac5=0.f, ac6=0.f, ac7=0.f;

        int k = 0;
        for (; k + 8 <= m; k += 8){
            int sA = lcsr[base+k+q];
            int sB = lcsr[base+k+4+q];
            float aA = asrc[(size_t)sA*NH+head];
            float aB = asrc[(size_t)sB*NH+head];
            uint4 uA = hb4[(size_t)sA*16 + l15];
            uint4 uB = hb4[(size_t)sB*16 + l15];
            float vA=aA+ad_h; vA=fmaxf(vA,SLOPE*vA); float pA=__expf(vA);
            float vB=aB+ad_h; vB=fmaxf(vB,SLOPE*vB); float pB=__expf(vB);
            ssum += pA + pB;
            ac0 = fmaf(pA,blo(uA.x), fmaf(pB,blo(uB.x), ac0));
            ac1 = fmaf(pA,bhi(uA.x), fmaf(pB,bhi(uB.x), ac1));
            ac2 = fmaf(pA,blo(uA.y), fmaf(pB,blo(uB.y), ac2));
            ac3 = fmaf(pA,bhi(uA.y), fmaf(pB,bhi(uB.y), ac3));
            ac4 = fmaf(pA,blo(uA.z), fmaf(pB,blo(uB.z), ac4));
            ac5 = fmaf(pA,bhi(uA.z), fmaf(pB,bhi(uB.z), ac5));
            ac6 = fmaf(pA,blo(uA.w), fmaf(pB,blo(uB.w), ac6));
            ac7 = fmaf(pA,bhi(uA.w), fmaf(pB,bhi(uB.w), ac7));
        }
        for (; k < m; k += 4){
            int r = m - k;
            if (q < r){
                int s = lcsr[base+k+q];
                float a0 = asrc[(size_t)s*NH+head];
                uint4 u = hb4[(size_t)s*16 + l15];
                float v = a0 + ad_h; v = fmaxf(v, SLOPE*v);
                float p = __expf(v);
                ssum += p;
                ac0 = fmaf(p, blo(u.x), ac0);
                ac1 = fmaf(p, bhi(u.x), ac1);
                ac2 = fmaf(p, blo(u.y), ac2);
                ac3 = fmaf(p, bhi(u.y), ac3);
                ac4 = fmaf(p, blo(u.z), ac4);
                ac5 = fmaf(p, bhi(u.z), ac5);
                ac6 = fmaf(p, blo(u.w), ac6);
                ac7 = fmaf(p, bhi(u.w), ac7);
            }
        }
        // combine the four quarter partial sums (same l15 => same channels/head)
        ssum += __shfl_xor(ssum, 16); ssum += __shfl_xor(ssum, 32);
        ac0 += __shfl_xor(ac0, 16); ac0 += __shfl_xor(ac0, 32);
        ac1 += __shfl_xor(ac1, 16); ac1 += __shfl_xor(ac1, 32);
        ac2 += __shfl_xor(ac2, 16); ac2 += __shfl_xor(ac2, 32);
        ac3 += __shfl_xor(ac3, 16); ac3 += __shfl_xor(ac3, 32);
        ac4 += __shfl_xor(ac4, 16); ac4 += __shfl_xor(ac4, 32);
        ac5 += __shfl_xor(ac5, 16); ac5 += __shfl_xor(ac5, 32);
        ac6 += __shfl_xor(ac6, 16); ac6 += __shfl_xor(ac6, 32);
        ac7 += __shfl_xor(ac7, 16); ac7 += __shfl_xor(ac7, 32);
        if (q == 0){
            float inv = 1.f / (ssum + 1e-16f);
            float4 o0 = make_float4(ac0*inv + bi0.x, ac1*inv + bi0.y,
                                    ac2*inv + bi0.z, ac3*inv + bi0.w);
            float4 o1 = make_float4(ac4*inv + bi1.x, ac5*inv + bi1.y,
                                    ac6*inv + bi1.z, ac7*inv + bi1.w);
            float* op = out + (size_t)d*HF + 8*l15;
            *(float4*)op     = o0;
            *(float4*)(op+4) = o1;
        }
    }
}

extern "C" void kernel_launch(void* const* d_in, const int* in_sizes, int n_in,
                              void* d_out, int out_size, void* d_ws, size_t ws_size,
                              hipStream_t stream)
{
    const float* x    = (const float*)d_in[0];
    const float* w    = (const float*)d_in[1];
    const float* a    = (const float*)d_in[2];
    const float* bias = (const float*)d_in[3];
    const int* esrc   = (const int*)d_in[4];
    const int* edst   = (const int*)d_in[5];
    float* out = (float*)d_out;

    // ws: wfrag s16[16384] | wafrag s16[2048] | hb u32[NN*64] | asrc f32[NN*4]
    //   | adst f32[NN*4] | parr u32[PNB*CAP] | cnt i32[PNB]
    short* wfrag  = (short*)d_ws;
    short* wafrag = wfrag + 16384;
    unsigned int* hb = (unsigned int*)(wafrag + 2048);
    float* as   = (float*)(hb + (size_t)NN*64);
    float* ad   = as + (size_t)NN*NH;
    unsigned int* parr = (unsigned int*)(ad + (size_t)NN*NH);
    int* cnt    = (int*)(parr + (size_t)PNB*CAP);

    hipLaunchKernelGGL(prep_k, dim3(1), dim3(1024), 0, stream,
                       w, a, wfrag, wafrag, cnt);
    hipLaunchKernelGGL(fused_k, dim3(NMF + NPART + 1), dim3(256), 0, stream,
                       x, wfrag, wafrag, hb, as, ad, esrc, edst, cnt, parr);
    hipLaunchKernelGGL(gather_k, dim3(PNB), dim3(256), 0, stream,
                       cnt, parr, as, ad, hb, bias, out);
}